// Round 9
// baseline (5226.018 us; speedup 1.0000x reference)
//
#include <hip/hip_runtime.h>
#include <math.h>

// Problem constants (from reference: B=4, S=1024, D=512, COMP=4)
#define S 1024
#define D 512
#define NCOMP (S / 4)        // 256
#define STEPS (S - NCOMP)    // 768
#define NEG_INF (-__builtin_inff())

// Module-persistent iteration counter. merge dispatch _ord k runs with
// g_iter = k+1:  even _ord -> g_iter odd  -> SINGLE (round-8 single, control)
//                odd  _ord -> g_iter even -> PAIRED (2 samples per wave)
__device__ int g_iter = 0;

__device__ __forceinline__ int   f2i(float x) { return __builtin_bit_cast(int, x); }
__device__ __forceinline__ float i2f(int x)   { return __builtin_bit_cast(float, x); }
__device__ __forceinline__ int   rfl(int x)   { return __builtin_amdgcn_readfirstlane(x); }

// Monotone float->uint key (strictly >0 for any non-NaN float).
__device__ __forceinline__ unsigned fkey(float f) {
    unsigned u = __builtin_bit_cast(unsigned, f);
    return (u & 0x80000000u) ? ~u : (u | 0x80000000u);
}
__device__ __forceinline__ float unfkey(unsigned k) {
    unsigned u = (k & 0x80000000u) ? (k & 0x7fffffffu) : ~k;
    return __builtin_bit_cast(float, u);
}

// Full-wave sum via DPP; total lands in lane 63. Same order as all prior rounds.
__device__ __forceinline__ float wave_sum63(float x) {
    x += i2f(__builtin_amdgcn_update_dpp(0, f2i(x), 0x111, 0xF, 0xF, true));
    x += i2f(__builtin_amdgcn_update_dpp(0, f2i(x), 0x112, 0xF, 0xF, true));
    x += i2f(__builtin_amdgcn_update_dpp(0, f2i(x), 0x114, 0xF, 0xF, true));
    x += i2f(__builtin_amdgcn_update_dpp(0, f2i(x), 0x118, 0xF, 0xF, true));
    x += i2f(__builtin_amdgcn_update_dpp(0, f2i(x), 0x142, 0xA, 0xF, true));
    x += i2f(__builtin_amdgcn_update_dpp(0, f2i(x), 0x143, 0xC, 0xF, true));
    return x;
}

#define AMAX_STEP(ctrl, rm) do {                                                        \
    unsigned ok_ = (unsigned)__builtin_amdgcn_update_dpp((int)key, (int)key, (ctrl), (rm), 0xF, false); \
    int      oi_ = __builtin_amdgcn_update_dpp(bi, bi, (ctrl), (rm), 0xF, false);        \
    bool tk_ = (ok_ > key) || ((ok_ == key) && (oi_ < bi));                              \
    key = tk_ ? ok_ : key; bi = tk_ ? oi_ : bi;                                          \
} while (0)

struct Row { float4 a, b; };

__device__ __forceinline__ Row row_load(const float* vals, int slot, int lane) {
    const float4* p = (const float4*)(vals + (size_t)slot * D);
    Row r; r.a = p[lane * 2]; r.b = p[lane * 2 + 1]; return r;
}
__device__ __forceinline__ void row_store(float* vals, int slot, int lane, Row r) {
    float4* p = (float4*)(vals + (size_t)slot * D);
    p[lane * 2] = r.a; p[lane * 2 + 1] = r.b;
}
__device__ __forceinline__ Row row_avg(Row x, Row y) {
    Row r;
    r.a.x = (x.a.x + y.a.x) * 0.5f; r.a.y = (x.a.y + y.a.y) * 0.5f;
    r.a.z = (x.a.z + y.a.z) * 0.5f; r.a.w = (x.a.w + y.a.w) * 0.5f;
    r.b.x = (x.b.x + y.b.x) * 0.5f; r.b.y = (x.b.y + y.b.y) * 0.5f;
    r.b.z = (x.b.z + y.b.z) * 0.5f; r.b.w = (x.b.w + y.b.w) * 0.5f;
    return r;
}
// Fixed accumulation order (identical to all prior rounds).
__device__ __forceinline__ float dot8_partial(Row x, Row y) {
    float acc = x.a.x * y.a.x;
    acc += x.a.y * y.a.y; acc += x.a.z * y.a.z; acc += x.a.w * y.a.w;
    acc += x.b.x * y.b.x; acc += x.b.y * y.b.y; acc += x.b.z * y.b.z; acc += x.b.w * y.b.w;
    return acc;
}
__device__ __forceinline__ int lsr(int s) { return ((unsigned)s < (unsigned)S) ? s : 0; }
__device__ __forceinline__ int lsl(int s) { return ((unsigned)s <= (unsigned)S) ? s : 0; }

// LDS argmax: slot layout s = lane + 64k, ties -> smallest slot.
__device__ __forceinline__ void lds_argmax(const float* dist, int lane, float& v1, int& i1) {
    float av[16];
#pragma unroll
    for (int k = 0; k < 16; ++k) av[k] = dist[lane + 64 * k];
    float v8[8]; int k8[8];
#pragma unroll
    for (int k = 0; k < 8; ++k) { bool tk = av[k+8] > av[k]; v8[k] = tk ? av[k+8] : av[k]; k8[k] = tk ? (k+8) : k; }
    float v4[4]; int k4[4];
#pragma unroll
    for (int k = 0; k < 4; ++k) { bool tk = v8[k+4] > v8[k]; v4[k] = tk ? v8[k+4] : v8[k]; k4[k] = tk ? k8[k+4] : k8[k]; }
    float v2[2]; int k2[2];
#pragma unroll
    for (int k = 0; k < 2; ++k) { bool tk = v4[k+2] > v4[k]; v2[k] = tk ? v4[k+2] : v4[k]; k2[k] = tk ? k4[k+2] : k4[k]; }
    bool tk1 = v2[1] > v2[0];
    float lv = tk1 ? v2[1] : v2[0];
    int   lk = tk1 ? k2[1] : k2[0];
    unsigned key = fkey(lv);
    int bi = lane | (lk << 6);
    AMAX_STEP(0x111, 0xF); AMAX_STEP(0x112, 0xF);
    AMAX_STEP(0x114, 0xF); AMAX_STEP(0x118, 0xF);
    AMAX_STEP(0x142, 0xA); AMAX_STEP(0x143, 0xC);
    i1 = __builtin_amdgcn_readlane(bi, 63);
    v1 = unfkey((unsigned)__builtin_amdgcn_readlane((int)key, 63));
}

// ===== SINGLE: round-8 single path verbatim (deferred 2nd-neighbor loads) ===
__device__ __attribute__((noinline)) void merge_single(float* __restrict__ vb,
                                                       const float* __restrict__ sd,
                                                       int* __restrict__ outIdx, int lane) {
    __shared__ int4 linksB[S + 1];
    __shared__ float distB[S];
    int4* links = linksB; float* dist = distB;
    const int* li32 = (const int*)linksB;

    for (int s = lane; s <= S; s += 64)
        links[s] = (s >= S) ? make_int4(S, S, S, 0)
                            : make_int4(s - 1, s + 1, (s + 2 <= S) ? (s + 2) : S, 0);
#pragma unroll
    for (int k = 0; k < 16; ++k) dist[lane + 64 * k] = sd[lane + 64 * k];

    float v1; int i1;
    lds_argmax(dist, lane, v1, i1);
    int m = i1;
    int4 L0 = links[m];
    int p = rfl(L0.x);
    int r = rfl(L0.y);
    int q = rfl(L0.z);
    bool hasp = (p >= 0), hasq = (q < S);
    int pp = hasp ? rfl(links[lsl(p)].x) : -1;
    int nq = hasq ? rfl(links[lsl(q)].y) : S;
    Row Rp  = row_load(vb, lsr(p),  lane);
    Row Rm  = row_load(vb, m,       lane);
    Row Rr  = row_load(vb, r,       lane);
    Row Rq  = row_load(vb, lsr(q),  lane);
    bool pendP = false, pendQ = false;
    Row vmprev = Rm;

#pragma unroll 1
    for (int t = 0; t < STEPS; ++t) {
        Row RppL = row_load(vb, lsr(pp), lane);
        Row RnqL = row_load(vb, lsr(nq), lane);
        int wnnq = li32[lsl(nq) * 4 + 1];
        int wnpp = li32[lsl(pp) * 4 + 0];

        if (lane == 0) {
            links[m].y = q; links[m].z = nq;
            if (hasp) links[p].z = q;
            if (hasq) links[q].x = m;
            dist[m] = NEG_INF; dist[r] = NEG_INF;
            if (hasp) dist[p] = NEG_INF;
        }
        Row vm = row_avg(Rm, Rr);
        row_store(vb, m, lane, vm);
        if (t + 1 >= STEPS) break;

        float sp_ = wave_sum63(dot8_partial(Rp, vm));
        float sq_ = wave_sum63(dot8_partial(vm, Rq));
        float ndp = hasp ? i2f(__builtin_amdgcn_readlane(f2i(sp_), 63)) : NEG_INF;
        float ndm = hasq ? i2f(__builtin_amdgcn_readlane(f2i(sq_), 63)) : NEG_INF;

        lds_argmax(dist, lane, v1, i1);

        float best = v1; int bi = i1;
        if (hasp && (ndp > best || (ndp == best && p < bi))) { best = ndp; bi = p; }
        if (hasq && (ndm > best || (ndm == best && m < bi))) { best = ndm; bi = m; }
        const int m2 = bi;

        if (lane == 0) {
            if (hasp) dist[p] = ndp;
            if (hasq) dist[m] = ndm;
        }

        int4 Li = links[lsl(i1)];
        int p2 = rfl(Li.x);
        int r2 = rfl(Li.y);
        int q2 = rfl(Li.z);
        int pp2 = rfl(li32[lsl(p2) * 4 + 0]);
        int nq2 = rfl(li32[lsl(q2) * 4 + 1]);
        Row Si = row_load(vb, lsr(i1), lane);
        Row Sr = row_load(vb, lsr(r2), lane);
        Row Sp = (p2 == m) ? vm : row_load(vb, lsr(p2), lane);
        Row Sq = (q2 == m) ? vm : row_load(vb, lsr(q2), lane);

        Row Rpp_eff = pendP ? vmprev : RppL;
        Row Rnq_eff = pendQ ? vmprev : RnqL;

        if (m2 == m) {
            Rm = vm; Rr = Rq; Rq = Rnq_eff;
            r = q; q = nq; nq = rfl(wnnq);
            hasq = (q < S);
            pendP = false; pendQ = false;
        } else if (m2 == p) {
            Rr = vm; Rm = Rp; Rp = Rpp_eff;
            r = m; m = p; p = pp; pp = rfl(wnpp);
            hasp = (p >= 0);
            pendP = false; pendQ = false;
        } else {
            pendP = (pp2 == m); pendQ = (nq2 == m); vmprev = vm;
            m = i1; p = p2; r = r2; q = q2; pp = pp2; nq = nq2;
            Rm = Si; Rr = Sr; Rp = Sp; Rq = Sq;
            hasp = (p >= 0); hasq = (q < S);
        }
    }

    if (lane == 0) {
        int s = 0;
        for (int i = 0; i < NCOMP; i += 2) {
            outIdx[i] = s;
            int4 Ls = links[s];
            if (i + 1 < NCOMP) outIdx[i + 1] = Ls.y;
            s = Ls.z;
        }
    }
}

// ===== PAIRED: two independent samples interleaved in one wave ==============
// Each phase of the single-B iteration runs for sample 0 then sample 1; the
// two dependence chains share no data, so each sample's LDS/VMEM latency is
// covered by the other's instructions. All state statically accessed.
struct MState {
    float* vb;
    int4* links; float* dist; const int* li32;
    int m, p, r, q, pp, nq;
    bool hasp, hasq, pendP, pendQ;
    Row Rp, Rm, Rr, Rq, vmprev;
    // cross-phase per-iteration temporaries
    Row RppL, RnqL; int wnnq, wnpp;
    Row vm;
    float ndp, ndm;
    float v1; int i1; int m2;
    int p2, r2, q2, pp2, nq2;
    Row Si, Sr, Sp, Sq;
};

__device__ __forceinline__ void ph_init(MState& st, const float* sd, int lane) {
    for (int s = lane; s <= S; s += 64)
        st.links[s] = (s >= S) ? make_int4(S, S, S, 0)
                               : make_int4(s - 1, s + 1, (s + 2 <= S) ? (s + 2) : S, 0);
#pragma unroll
    for (int k = 0; k < 16; ++k) st.dist[lane + 64 * k] = sd[lane + 64 * k];
}
__device__ __forceinline__ void ph_start(MState& st, int lane) {
    float v1; int i1;
    lds_argmax(st.dist, lane, v1, i1);
    st.m = i1;
    int4 L0 = st.links[st.m];
    st.p = rfl(L0.x); st.r = rfl(L0.y); st.q = rfl(L0.z);
    st.hasp = (st.p >= 0); st.hasq = (st.q < S);
    st.pp = st.hasp ? rfl(st.links[lsl(st.p)].x) : -1;
    st.nq = st.hasq ? rfl(st.links[lsl(st.q)].y) : S;
    st.Rp = row_load(st.vb, lsr(st.p), lane);
    st.Rm = row_load(st.vb, st.m,      lane);
    st.Rr = row_load(st.vb, st.r,      lane);
    st.Rq = row_load(st.vb, lsr(st.q), lane);
    st.pendP = false; st.pendQ = false;
    st.vmprev = st.Rm;
}
__device__ __forceinline__ void phT(MState& st, int lane) {   // early refills
    st.RppL = row_load(st.vb, lsr(st.pp), lane);
    st.RnqL = row_load(st.vb, lsr(st.nq), lane);
    st.wnnq = st.li32[lsl(st.nq) * 4 + 1];
    st.wnpp = st.li32[lsl(st.pp) * 4 + 0];
}
__device__ __forceinline__ void ph1(MState& st, int lane) {   // maint + poison
    if (lane == 0) {
        st.links[st.m].y = st.q; st.links[st.m].z = st.nq;
        if (st.hasp) st.links[st.p].z = st.q;
        if (st.hasq) st.links[st.q].x = st.m;
        st.dist[st.m] = NEG_INF; st.dist[st.r] = NEG_INF;
        if (st.hasp) st.dist[st.p] = NEG_INF;
    }
}
__device__ __forceinline__ void ph2(MState& st, int lane) {   // vm + store
    st.vm = row_avg(st.Rm, st.Rr);
    row_store(st.vb, st.m, lane, st.vm);
}
__device__ __forceinline__ void ph3(MState& st, int lane) {   // dots
    float sp_ = wave_sum63(dot8_partial(st.Rp, st.vm));
    float sq_ = wave_sum63(dot8_partial(st.vm, st.Rq));
    st.ndp = st.hasp ? i2f(__builtin_amdgcn_readlane(f2i(sp_), 63)) : NEG_INF;
    st.ndm = st.hasq ? i2f(__builtin_amdgcn_readlane(f2i(sq_), 63)) : NEG_INF;
}
__device__ __forceinline__ void ph4(MState& st, int lane) {   // masked argmax
    lds_argmax(st.dist, lane, st.v1, st.i1);
}
__device__ __forceinline__ void ph5(MState& st, int lane) {   // fixup + restore
    float best = st.v1; int bi = st.i1;
    if (st.hasp && (st.ndp > best || (st.ndp == best && st.p < bi))) { best = st.ndp; bi = st.p; }
    if (st.hasq && (st.ndm > best || (st.ndm == best && st.m < bi))) { best = st.ndm; bi = st.m; }
    st.m2 = bi;
    if (lane == 0) {
        if (st.hasp) st.dist[st.p] = st.ndp;
        if (st.hasq) st.dist[st.m] = st.ndm;
    }
}
__device__ __forceinline__ void ph7(MState& st, int lane) {   // spec hop+loads
    int4 Li = st.links[lsl(st.i1)];
    st.p2 = rfl(Li.x); st.r2 = rfl(Li.y); st.q2 = rfl(Li.z);
    st.pp2 = rfl(st.li32[lsl(st.p2) * 4 + 0]);
    st.nq2 = rfl(st.li32[lsl(st.q2) * 4 + 1]);
    st.Si = row_load(st.vb, lsr(st.i1), lane);
    st.Sr = row_load(st.vb, lsr(st.r2), lane);
    st.Sp = (st.p2 == st.m) ? st.vm : row_load(st.vb, lsr(st.p2), lane);
    st.Sq = (st.q2 == st.m) ? st.vm : row_load(st.vb, lsr(st.q2), lane);
}
__device__ __forceinline__ void ph8(MState& st) {             // advance
    Row Rpp_eff = st.pendP ? st.vmprev : st.RppL;
    Row Rnq_eff = st.pendQ ? st.vmprev : st.RnqL;
    if (st.m2 == st.m) {
        st.Rm = st.vm; st.Rr = st.Rq; st.Rq = Rnq_eff;
        st.r = st.q; st.q = st.nq; st.nq = rfl(st.wnnq);
        st.hasq = (st.q < S);
        st.pendP = false; st.pendQ = false;
    } else if (st.m2 == st.p) {
        st.Rr = st.vm; st.Rm = st.Rp; st.Rp = Rpp_eff;
        st.r = st.m; st.m = st.p; st.p = st.pp; st.pp = rfl(st.wnpp);
        st.hasp = (st.p >= 0);
        st.pendP = false; st.pendQ = false;
    } else {
        st.pendP = (st.pp2 == st.m); st.pendQ = (st.nq2 == st.m); st.vmprev = st.vm;
        st.m = st.i1; st.p = st.p2; st.r = st.r2; st.q = st.q2; st.pp = st.pp2; st.nq = st.nq2;
        st.Rm = st.Si; st.Rr = st.Sr; st.Rp = st.Sp; st.Rq = st.Sq;
        st.hasp = (st.p >= 0); st.hasq = (st.q < S);
    }
}

__device__ __attribute__((noinline)) void merge_pair(float* __restrict__ vb0,
                                                     float* __restrict__ aux0,
                                                     float* __restrict__ vb1,
                                                     float* __restrict__ aux1,
                                                     int lane) {
    __shared__ int4 linksP[2][S + 1];
    __shared__ float distP[2][S];

    MState s0, s1;
    s0.vb = vb0; s0.links = linksP[0]; s0.dist = distP[0]; s0.li32 = (const int*)linksP[0];
    s1.vb = vb1; s1.links = linksP[1]; s1.dist = distP[1]; s1.li32 = (const int*)linksP[1];

    ph_init(s0, aux0, lane);
    ph_init(s1, aux1, lane);
    ph_start(s0, lane);
    ph_start(s1, lane);

#pragma unroll 1
    for (int t = 0; t < STEPS; ++t) {
        phT(s0, lane); phT(s1, lane);
        ph1(s0, lane); ph1(s1, lane);
        ph2(s0, lane); ph2(s1, lane);
        if (t + 1 >= STEPS) break;
        ph3(s0, lane); ph3(s1, lane);
        ph4(s0, lane); ph4(s1, lane);
        ph5(s0, lane); ph5(s1, lane);
        ph7(s0, lane); ph7(s1, lane);
        ph8(s0);       ph8(s1);
    }

    if (lane == 0) {
        int* outIdx0 = (int*)(aux0 + S);
        int* outIdx1 = (int*)(aux1 + S);
        int s = 0;
        for (int i = 0; i < NCOMP; i += 2) {
            outIdx0[i] = s;
            int4 Ls = s0.links[s];
            if (i + 1 < NCOMP) outIdx0[i + 1] = Ls.y;
            s = Ls.z;
        }
        s = 0;
        for (int i = 0; i < NCOMP; i += 2) {
            outIdx1[i] = s;
            int4 Ls = s1.links[s];
            if (i + 1 < NCOMP) outIdx1[i + 1] = Ls.y;
            s = Ls.z;
        }
    }
}

// ---- K1: copy x->vals (if needed) + 1023 initial pair dots ----
__global__ __launch_bounds__(256) void init_kernel(const float* __restrict__ x,
                                                   float* __restrict__ vals,
                                                   float* __restrict__ out) {
    const int blk = blockIdx.x, b = blk >> 4, g = blk & 15;
    const int tid = threadIdx.x, lane = tid & 63, w = tid >> 6;
    const float* xb = x + (size_t)b * S * D;
    if (blk == 0 && tid == 0) g_iter = g_iter + 1;   // flip A/B parity
    if (vals != x) {
        float* vb = vals + (size_t)b * S * D;
        const float4* s4 = (const float4*)xb;
        float4* d4 = (float4*)vb;
        const int base = g * (S * D / 4 / 16);
        for (int i = tid; i < S * D / 4 / 16; i += 256) d4[base + i] = s4[base + i];
    }
    float* sd = out + (size_t)b * NCOMP * D;   // sdist staged in out chunk b
#pragma unroll 1
    for (int j = 0; j < 16; ++j) {
        int pr = g * 64 + w * 16 + j;
        if (pr < S - 1) {
            Row A = row_load(xb, pr, lane);
            Row B = row_load(xb, pr + 1, lane);
            float t = wave_sum63(dot8_partial(A, B));
            if (lane == 63) sd[pr] = t;
        }
    }
    if (g == 0 && tid == 0) sd[S - 1] = NEG_INF;
}

// ---- K2: serial merge + L2 warm waves; A/B single (4 blk) vs paired (2 blk) -
__global__ __launch_bounds__(256, 1) void merge_kernel(float* __restrict__ vals,
                                                       float* __restrict__ out,
                                                       int nb) {
    const int blk = blockIdx.x, tid = threadIdx.x;
    const int lane = tid & 63, wave = tid >> 6;
    const int paired = !(g_iter & 1);   // odd _ord -> paired

    if (!paired) {
        const int b = blk;
        float* vb = vals + (size_t)b * S * D;
        float* aux = out + (size_t)b * NCOMP * D;
        if (wave != 0) {
            float acc = 0.0f;
            for (int s = wave - 1; s < S; s += 3) {
                Row rr = row_load(vb, s, lane);
                acc += rr.a.x + rr.b.w;
            }
            if (acc == 1234.5678f) out[2050] = acc;
            return;
        }
        merge_single(vb, aux, (int*)(aux + S), lane);
        return;
    }

    // paired: blocks 0..nb/2-1 each merge two samples; rest exit.
    if (blk >= (nb >> 1)) return;
    float* vb0  = vals + (size_t)(2 * blk)     * S * D;
    float* vb1  = vals + (size_t)(2 * blk + 1) * S * D;
    float* aux0 = out  + (size_t)(2 * blk)     * NCOMP * D;
    float* aux1 = out  + (size_t)(2 * blk + 1) * NCOMP * D;
    if (wave != 0) {
        // warm both samples' rows (3 waves, stride 3 over 2S rows)
        float acc = 0.0f;
        for (int s = wave - 1; s < 2 * S; s += 3) {
            float* vv = (s < S) ? vb0 : vb1;
            int row = (s < S) ? s : (s - S);
            Row rr = row_load(vv, row, lane);
            acc += rr.a.x + rr.b.w;
        }
        if (acc == 1234.5678f) out[2050] = acc;
        return;
    }
    merge_pair(vb0, aux0, vb1, aux1, lane);
}

// ---- K3: gather the first NCOMP surviving rows into out ----
__global__ __launch_bounds__(256) void gather_kernel(const float* __restrict__ vals,
                                                     float* __restrict__ out) {
    const int b = blockIdx.x, part = blockIdx.y;
    const float* vb = vals + (size_t)b * S * D;
    float* ob = out + (size_t)b * NCOMP * D;
    __shared__ int oi[NCOMP / 8];
    const int row0 = part * (NCOMP / 8);
    if (threadIdx.x < NCOMP / 8)
        oi[threadIdx.x] = ((const int*)(ob + S))[row0 + threadIdx.x];
    __syncthreads();
    const float4* v4 = (const float4*)vb;
    float4* o4 = (float4*)ob;
    const int per = (NCOMP / 8) * (D / 4);            // 4096 float4s per part
    for (int idx = threadIdx.x; idx < per; idx += 256) {
        int row = idx >> 7, c = idx & 127;
        o4[(size_t)(row0 + row) * (D / 4) + c] = v4[(size_t)oi[row] * (D / 4) + c];
    }
}

extern "C" void kernel_launch(void* const* d_in, const int* in_sizes, int n_in,
                              void* d_out, int out_size, void* d_ws, size_t ws_size,
                              hipStream_t stream) {
    const float* x = (const float*)d_in[0];
    float* out = (float*)d_out;
    const int b = in_sizes[0] / (S * D);   // 4
    const size_t need = (size_t)in_sizes[0] * sizeof(float);
    float* vals = (ws_size >= need) ? (float*)d_ws : (float*)x;
    init_kernel<<<dim3(16 * b), dim3(256), 0, stream>>>(x, vals, out);
    merge_kernel<<<dim3(b), dim3(256), 0, stream>>>(vals, out, b);
    gather_kernel<<<dim3(b, 8), dim3(256), 0, stream>>>(vals, out);
}

// Round 11
// 985.624 us; speedup vs baseline: 5.3022x; 5.3022x over previous
//
#include <hip/hip_runtime.h>
#include <math.h>

// Problem constants (from reference: B=4, S=1024, D=512, COMP=4)
#define S 1024
#define D 512
#define NCOMP (S / 4)        // 256
#define STEPS (S - NCOMP)    // 768
#define NEG_INF (-__builtin_inff())

// Module-persistent iteration counter. merge dispatch _ord k runs with
// g_iter = k+1:  even _ord -> g_iter odd  -> variant B (round-8 single, control)
//                odd  _ord -> g_iter even -> variant C (b128 argmax layout)
__device__ int g_iter = 0;

__device__ __forceinline__ int   f2i(float x) { return __builtin_bit_cast(int, x); }
__device__ __forceinline__ float i2f(int x)   { return __builtin_bit_cast(float, x); }
__device__ __forceinline__ int   rfl(int x)   { return __builtin_amdgcn_readfirstlane(x); }

// Monotone float->uint key (strictly >0 for any non-NaN float).
__device__ __forceinline__ unsigned fkey(float f) {
    unsigned u = __builtin_bit_cast(unsigned, f);
    return (u & 0x80000000u) ? ~u : (u | 0x80000000u);
}
__device__ __forceinline__ float unfkey(unsigned k) {
    unsigned u = (k & 0x80000000u) ? (k & 0x7fffffffu) : ~k;
    return __builtin_bit_cast(float, u);
}

// Full-wave sum via DPP; total lands in lane 63. Same order as all prior rounds.
__device__ __forceinline__ float wave_sum63(float x) {
    x += i2f(__builtin_amdgcn_update_dpp(0, f2i(x), 0x111, 0xF, 0xF, true));
    x += i2f(__builtin_amdgcn_update_dpp(0, f2i(x), 0x112, 0xF, 0xF, true));
    x += i2f(__builtin_amdgcn_update_dpp(0, f2i(x), 0x114, 0xF, 0xF, true));
    x += i2f(__builtin_amdgcn_update_dpp(0, f2i(x), 0x118, 0xF, 0xF, true));
    x += i2f(__builtin_amdgcn_update_dpp(0, f2i(x), 0x142, 0xA, 0xF, true));
    x += i2f(__builtin_amdgcn_update_dpp(0, f2i(x), 0x143, 0xC, 0xF, true));
    return x;
}

#define AMAX_STEP(ctrl, rm) do {                                                        \
    unsigned ok_ = (unsigned)__builtin_amdgcn_update_dpp((int)key, (int)key, (ctrl), (rm), 0xF, false); \
    int      oi_ = __builtin_amdgcn_update_dpp(bi, bi, (ctrl), (rm), 0xF, false);        \
    bool tk_ = (ok_ > key) || ((ok_ == key) && (oi_ < bi));                              \
    key = tk_ ? ok_ : key; bi = tk_ ? oi_ : bi;                                          \
} while (0)

struct Row { float4 a, b; };

__device__ __forceinline__ Row row_load(const float* vals, int slot, int lane) {
    const float4* p = (const float4*)(vals + (size_t)slot * D);
    Row r; r.a = p[lane * 2]; r.b = p[lane * 2 + 1]; return r;
}
__device__ __forceinline__ void row_store(float* vals, int slot, int lane, Row r) {
    float4* p = (float4*)(vals + (size_t)slot * D);
    p[lane * 2] = r.a; p[lane * 2 + 1] = r.b;
}
__device__ __forceinline__ Row row_avg(Row x, Row y) {
    Row r;
    r.a.x = (x.a.x + y.a.x) * 0.5f; r.a.y = (x.a.y + y.a.y) * 0.5f;
    r.a.z = (x.a.z + y.a.z) * 0.5f; r.a.w = (x.a.w + y.a.w) * 0.5f;
    r.b.x = (x.b.x + y.b.x) * 0.5f; r.b.y = (x.b.y + y.b.y) * 0.5f;
    r.b.z = (x.b.z + y.b.z) * 0.5f; r.b.w = (x.b.w + y.b.w) * 0.5f;
    return r;
}
// Fixed accumulation order (identical to all prior rounds).
__device__ __forceinline__ float dot8_partial(Row x, Row y) {
    float acc = x.a.x * y.a.x;
    acc += x.a.y * y.a.y; acc += x.a.z * y.a.z; acc += x.a.w * y.a.w;
    acc += x.b.x * y.b.x; acc += x.b.y * y.b.y; acc += x.b.z * y.b.z; acc += x.b.w * y.b.w;
    return acc;
}
__device__ __forceinline__ int lsr(int s) { return ((unsigned)s < (unsigned)S) ? s : 0; }
__device__ __forceinline__ int lsl(int s) { return ((unsigned)s <= (unsigned)S) ? s : 0; }

// ---- B-layout argmax: slot s = lane + 64k, b32 reads, ties -> smallest slot.
__device__ __forceinline__ void lds_argmax(const float* dist, int lane, float& v1, int& i1) {
    float av[16];
#pragma unroll
    for (int k = 0; k < 16; ++k) av[k] = dist[lane + 64 * k];
    float v8[8]; int k8[8];
#pragma unroll
    for (int k = 0; k < 8; ++k) { bool tk = av[k+8] > av[k]; v8[k] = tk ? av[k+8] : av[k]; k8[k] = tk ? (k+8) : k; }
    float v4[4]; int k4[4];
#pragma unroll
    for (int k = 0; k < 4; ++k) { bool tk = v8[k+4] > v8[k]; v4[k] = tk ? v8[k+4] : v8[k]; k4[k] = tk ? k8[k+4] : k8[k]; }
    float v2[2]; int k2[2];
#pragma unroll
    for (int k = 0; k < 2; ++k) { bool tk = v4[k+2] > v4[k]; v2[k] = tk ? v4[k+2] : v4[k]; k2[k] = tk ? k4[k+2] : k4[k]; }
    bool tk1 = v2[1] > v2[0];
    float lv = tk1 ? v2[1] : v2[0];
    int   lk = tk1 ? k2[1] : k2[0];
    unsigned key = fkey(lv);
    int bi = lane | (lk << 6);
    AMAX_STEP(0x111, 0xF); AMAX_STEP(0x112, 0xF);
    AMAX_STEP(0x114, 0xF); AMAX_STEP(0x118, 0xF);
    AMAX_STEP(0x142, 0xA); AMAX_STEP(0x143, 0xC);
    i1 = __builtin_amdgcn_readlane(bi, 63);
    v1 = unfkey((unsigned)__builtin_amdgcn_readlane((int)key, 63));
}

// ---- C-layout: slot s stored at (s>>4)*20 + (s&15); lane L owns slots
// [16L, 16L+15] in 16 contiguous floats (80B stride -> 16B-aligned regions,
// bank-starts spread over 8 groups -> <=2-way conflict). Argmax reads them
// with 4 ds_read_b128. Tie-break identical to B: per-lane tree keeps min j
// (= min slot in lane), bi = 16*lane + j = true slot id, DPP picks min bi.
__device__ __forceinline__ int adrC(int s) { return (s >> 4) * 20 + (s & 15); }

__device__ __forceinline__ void lds_argmax_c(const float* dist, int lane, float& v1, int& i1) {
    const float4* p4 = (const float4*)(dist + lane * 20);
    float4 q0 = p4[0], q1 = p4[1], q2 = p4[2], q3 = p4[3];
    float av[16] = { q0.x, q0.y, q0.z, q0.w, q1.x, q1.y, q1.z, q1.w,
                     q2.x, q2.y, q2.z, q2.w, q3.x, q3.y, q3.z, q3.w };
    float v8[8]; int k8[8];
#pragma unroll
    for (int k = 0; k < 8; ++k) { bool tk = av[k+8] > av[k]; v8[k] = tk ? av[k+8] : av[k]; k8[k] = tk ? (k+8) : k; }
    float v4[4]; int k4[4];
#pragma unroll
    for (int k = 0; k < 4; ++k) { bool tk = v8[k+4] > v8[k]; v4[k] = tk ? v8[k+4] : v8[k]; k4[k] = tk ? k8[k+4] : k8[k]; }
    float v2[2]; int k2[2];
#pragma unroll
    for (int k = 0; k < 2; ++k) { bool tk = v4[k+2] > v4[k]; v2[k] = tk ? v4[k+2] : v4[k]; k2[k] = tk ? k4[k+2] : k4[k]; }
    bool tk1 = v2[1] > v2[0];
    float lv = tk1 ? v2[1] : v2[0];
    int   lk = tk1 ? k2[1] : k2[0];
    unsigned key = fkey(lv);
    int bi = (lane << 4) | lk;
    AMAX_STEP(0x111, 0xF); AMAX_STEP(0x112, 0xF);
    AMAX_STEP(0x114, 0xF); AMAX_STEP(0x118, 0xF);
    AMAX_STEP(0x142, 0xA); AMAX_STEP(0x143, 0xC);
    i1 = __builtin_amdgcn_readlane(bi, 63);
    v1 = unfkey((unsigned)__builtin_amdgcn_readlane((int)key, 63));
}

// ===== Variant B: round-8 single path verbatim (control) ====================
__device__ __attribute__((noinline)) void merge_single(float* __restrict__ vb,
                                                       const float* __restrict__ sd,
                                                       int* __restrict__ outIdx, int lane) {
    __shared__ int4 linksB[S + 1];
    __shared__ float distB[S];
    int4* links = linksB; float* dist = distB;
    const int* li32 = (const int*)linksB;

    for (int s = lane; s <= S; s += 64)
        links[s] = (s >= S) ? make_int4(S, S, S, 0)
                            : make_int4(s - 1, s + 1, (s + 2 <= S) ? (s + 2) : S, 0);
#pragma unroll
    for (int k = 0; k < 16; ++k) dist[lane + 64 * k] = sd[lane + 64 * k];

    float v1; int i1;
    lds_argmax(dist, lane, v1, i1);
    int m = i1;
    int4 L0 = links[m];
    int p = rfl(L0.x);
    int r = rfl(L0.y);
    int q = rfl(L0.z);
    bool hasp = (p >= 0), hasq = (q < S);
    int pp = hasp ? rfl(links[lsl(p)].x) : -1;
    int nq = hasq ? rfl(links[lsl(q)].y) : S;
    Row Rp  = row_load(vb, lsr(p),  lane);
    Row Rm  = row_load(vb, m,       lane);
    Row Rr  = row_load(vb, r,       lane);
    Row Rq  = row_load(vb, lsr(q),  lane);
    bool pendP = false, pendQ = false;
    Row vmprev = Rm;

#pragma unroll 1
    for (int t = 0; t < STEPS; ++t) {
        Row RppL = row_load(vb, lsr(pp), lane);
        Row RnqL = row_load(vb, lsr(nq), lane);
        int wnnq = li32[lsl(nq) * 4 + 1];
        int wnpp = li32[lsl(pp) * 4 + 0];

        if (lane == 0) {
            links[m].y = q; links[m].z = nq;
            if (hasp) links[p].z = q;
            if (hasq) links[q].x = m;
            dist[m] = NEG_INF; dist[r] = NEG_INF;
            if (hasp) dist[p] = NEG_INF;
        }
        Row vm = row_avg(Rm, Rr);
        row_store(vb, m, lane, vm);
        if (t + 1 >= STEPS) break;

        float sp_ = wave_sum63(dot8_partial(Rp, vm));
        float sq_ = wave_sum63(dot8_partial(vm, Rq));
        float ndp = hasp ? i2f(__builtin_amdgcn_readlane(f2i(sp_), 63)) : NEG_INF;
        float ndm = hasq ? i2f(__builtin_amdgcn_readlane(f2i(sq_), 63)) : NEG_INF;

        lds_argmax(dist, lane, v1, i1);

        float best = v1; int bi = i1;
        if (hasp && (ndp > best || (ndp == best && p < bi))) { best = ndp; bi = p; }
        if (hasq && (ndm > best || (ndm == best && m < bi))) { best = ndm; bi = m; }
        const int m2 = bi;

        if (lane == 0) {
            if (hasp) dist[p] = ndp;
            if (hasq) dist[m] = ndm;
        }

        int4 Li = links[lsl(i1)];
        int p2 = rfl(Li.x);
        int r2 = rfl(Li.y);
        int q2 = rfl(Li.z);
        int pp2 = rfl(li32[lsl(p2) * 4 + 0]);
        int nq2 = rfl(li32[lsl(q2) * 4 + 1]);
        Row Si = row_load(vb, lsr(i1), lane);
        Row Sr = row_load(vb, lsr(r2), lane);
        Row Sp = (p2 == m) ? vm : row_load(vb, lsr(p2), lane);
        Row Sq = (q2 == m) ? vm : row_load(vb, lsr(q2), lane);

        Row Rpp_eff = pendP ? vmprev : RppL;
        Row Rnq_eff = pendQ ? vmprev : RnqL;

        if (m2 == m) {
            Rm = vm; Rr = Rq; Rq = Rnq_eff;
            r = q; q = nq; nq = rfl(wnnq);
            hasq = (q < S);
            pendP = false; pendQ = false;
        } else if (m2 == p) {
            Rr = vm; Rm = Rp; Rp = Rpp_eff;
            r = m; m = p; p = pp; pp = rfl(wnpp);
            hasp = (p >= 0);
            pendP = false; pendQ = false;
        } else {
            pendP = (pp2 == m); pendQ = (nq2 == m); vmprev = vm;
            m = i1; p = p2; r = r2; q = q2; pp = pp2; nq = nq2;
            Rm = Si; Rr = Sr; Rp = Sp; Rq = Sq;
            hasp = (p >= 0); hasq = (q < S);
        }
    }

    if (lane == 0) {
        int s = 0;
        for (int i = 0; i < NCOMP; i += 2) {
            outIdx[i] = s;
            int4 Ls = links[s];
            if (i + 1 < NCOMP) outIdx[i + 1] = Ls.y;
            s = Ls.z;
        }
    }
}

// ===== Variant C: identical to B except dist layout + b128 argmax ===========
__device__ __attribute__((noinline)) void merge_single_c(float* __restrict__ vb,
                                                         const float* __restrict__ sd,
                                                         int* __restrict__ outIdx, int lane) {
    __shared__ int4 linksC[S + 1];
    __shared__ float distC[64 * 20];   // 20 floats per lane, slots via adrC
    int4* links = linksC; float* dist = distC;
    const int* li32 = (const int*)linksC;

    for (int s = lane; s <= S; s += 64)
        links[s] = (s >= S) ? make_int4(S, S, S, 0)
                            : make_int4(s - 1, s + 1, (s + 2 <= S) ? (s + 2) : S, 0);
    // fill own 16 slots contiguously (slot 16*lane+j at dist[lane*20+j])
#pragma unroll
    for (int j = 0; j < 16; ++j) dist[lane * 20 + j] = sd[16 * lane + j];

    float v1; int i1;
    lds_argmax_c(dist, lane, v1, i1);
    int m = i1;
    int4 L0 = links[m];
    int p = rfl(L0.x);
    int r = rfl(L0.y);
    int q = rfl(L0.z);
    bool hasp = (p >= 0), hasq = (q < S);
    int pp = hasp ? rfl(links[lsl(p)].x) : -1;
    int nq = hasq ? rfl(links[lsl(q)].y) : S;
    Row Rp  = row_load(vb, lsr(p),  lane);
    Row Rm  = row_load(vb, m,       lane);
    Row Rr  = row_load(vb, r,       lane);
    Row Rq  = row_load(vb, lsr(q),  lane);
    bool pendP = false, pendQ = false;
    Row vmprev = Rm;

#pragma unroll 1
    for (int t = 0; t < STEPS; ++t) {
        Row RppL = row_load(vb, lsr(pp), lane);
        Row RnqL = row_load(vb, lsr(nq), lane);
        int wnnq = li32[lsl(nq) * 4 + 1];
        int wnpp = li32[lsl(pp) * 4 + 0];

        if (lane == 0) {
            links[m].y = q; links[m].z = nq;
            if (hasp) links[p].z = q;
            if (hasq) links[q].x = m;
            dist[adrC(m)] = NEG_INF; dist[adrC(r)] = NEG_INF;
            if (hasp) dist[adrC(p)] = NEG_INF;
        }
        Row vm = row_avg(Rm, Rr);
        row_store(vb, m, lane, vm);
        if (t + 1 >= STEPS) break;

        float sp_ = wave_sum63(dot8_partial(Rp, vm));
        float sq_ = wave_sum63(dot8_partial(vm, Rq));
        float ndp = hasp ? i2f(__builtin_amdgcn_readlane(f2i(sp_), 63)) : NEG_INF;
        float ndm = hasq ? i2f(__builtin_amdgcn_readlane(f2i(sq_), 63)) : NEG_INF;

        lds_argmax_c(dist, lane, v1, i1);

        float best = v1; int bi = i1;
        if (hasp && (ndp > best || (ndp == best && p < bi))) { best = ndp; bi = p; }
        if (hasq && (ndm > best || (ndm == best && m < bi))) { best = ndm; bi = m; }
        const int m2 = bi;

        if (lane == 0) {
            if (hasp) dist[adrC(p)] = ndp;
            if (hasq) dist[adrC(m)] = ndm;
        }

        int4 Li = links[lsl(i1)];
        int p2 = rfl(Li.x);
        int r2 = rfl(Li.y);
        int q2 = rfl(Li.z);
        int pp2 = rfl(li32[lsl(p2) * 4 + 0]);
        int nq2 = rfl(li32[lsl(q2) * 4 + 1]);
        Row Si = row_load(vb, lsr(i1), lane);
        Row Sr = row_load(vb, lsr(r2), lane);
        Row Sp = (p2 == m) ? vm : row_load(vb, lsr(p2), lane);
        Row Sq = (q2 == m) ? vm : row_load(vb, lsr(q2), lane);

        Row Rpp_eff = pendP ? vmprev : RppL;
        Row Rnq_eff = pendQ ? vmprev : RnqL;

        if (m2 == m) {
            Rm = vm; Rr = Rq; Rq = Rnq_eff;
            r = q; q = nq; nq = rfl(wnnq);
            hasq = (q < S);
            pendP = false; pendQ = false;
        } else if (m2 == p) {
            Rr = vm; Rm = Rp; Rp = Rpp_eff;
            r = m; m = p; p = pp; pp = rfl(wnpp);
            hasp = (p >= 0);
            pendP = false; pendQ = false;
        } else {
            pendP = (pp2 == m); pendQ = (nq2 == m); vmprev = vm;
            m = i1; p = p2; r = r2; q = q2; pp = pp2; nq = nq2;
            Rm = Si; Rr = Sr; Rp = Sp; Rq = Sq;
            hasp = (p >= 0); hasq = (q < S);
        }
    }

    if (lane == 0) {
        int s = 0;
        for (int i = 0; i < NCOMP; i += 2) {
            outIdx[i] = s;
            int4 Ls = links[s];
            if (i + 1 < NCOMP) outIdx[i + 1] = Ls.y;
            s = Ls.z;
        }
    }
}

// ---- K1: copy x->vals (if needed) + 1023 initial pair dots ----
__global__ __launch_bounds__(256) void init_kernel(const float* __restrict__ x,
                                                   float* __restrict__ vals,
                                                   float* __restrict__ out) {
    const int blk = blockIdx.x, b = blk >> 4, g = blk & 15;
    const int tid = threadIdx.x, lane = tid & 63, w = tid >> 6;
    const float* xb = x + (size_t)b * S * D;
    if (blk == 0 && tid == 0) g_iter = g_iter + 1;   // flip A/B parity
    if (vals != x) {
        float* vb = vals + (size_t)b * S * D;
        const float4* s4 = (const float4*)xb;
        float4* d4 = (float4*)vb;
        const int base = g * (S * D / 4 / 16);
        for (int i = tid; i < S * D / 4 / 16; i += 256) d4[base + i] = s4[base + i];
    }
    float* sd = out + (size_t)b * NCOMP * D;   // sdist staged in out chunk b
#pragma unroll 1
    for (int j = 0; j < 16; ++j) {
        int pr = g * 64 + w * 16 + j;
        if (pr < S - 1) {
            Row A = row_load(xb, pr, lane);
            Row B = row_load(xb, pr + 1, lane);
            float t = wave_sum63(dot8_partial(A, B));
            if (lane == 63) sd[pr] = t;
        }
    }
    if (g == 0 && tid == 0) sd[S - 1] = NEG_INF;
}

// ---- K2: serial merge (1 wave/sample) + L2 warm waves; B vs C by parity ----
__global__ __launch_bounds__(256, 1) void merge_kernel(float* __restrict__ vals,
                                                       float* __restrict__ out,
                                                       int nb) {
    const int blk = blockIdx.x, tid = threadIdx.x;
    const int b = blk, lane = tid & 63, wave = tid >> 6;
    float* vb = vals + (size_t)b * S * D;
    float* aux = out + (size_t)b * NCOMP * D;
    int* outIdx = (int*)(aux + S);

    if (wave != 0) {
        // L2 warm sweep: touch every row once so the merge wave's loads hit
        // this block's own XCD L2.
        float acc = 0.0f;
        for (int s = wave - 1; s < S; s += 3) {
            Row rr = row_load(vb, s, lane);
            acc += rr.a.x + rr.b.w;
        }
        if (acc == 1234.5678f) out[2050] = acc;   // keep loads live
        return;
    }

    if (g_iter & 1) merge_single(vb, aux, outIdx, lane);     // even _ord: B
    else            merge_single_c(vb, aux, outIdx, lane);   // odd  _ord: C
}

// ---- K3: gather the first NCOMP surviving rows into out ----
__global__ __launch_bounds__(256) void gather_kernel(const float* __restrict__ vals,
                                                     float* __restrict__ out) {
    const int b = blockIdx.x, part = blockIdx.y;
    const float* vb = vals + (size_t)b * S * D;
    float* ob = out + (size_t)b * NCOMP * D;
    __shared__ int oi[NCOMP / 8];
    const int row0 = part * (NCOMP / 8);
    if (threadIdx.x < NCOMP / 8)
        oi[threadIdx.x] = ((const int*)(ob + S))[row0 + threadIdx.x];
    __syncthreads();
    const float4* v4 = (const float4*)vb;
    float4* o4 = (float4*)ob;
    const int per = (NCOMP / 8) * (D / 4);            // 4096 float4s per part
    for (int idx = threadIdx.x; idx < per; idx += 256) {
        int row = idx >> 7, c = idx & 127;
        o4[(size_t)(row0 + row) * (D / 4) + c] = v4[(size_t)oi[row] * (D / 4) + c];
    }
}

extern "C" void kernel_launch(void* const* d_in, const int* in_sizes, int n_in,
                              void* d_out, int out_size, void* d_ws, size_t ws_size,
                              hipStream_t stream) {
    const float* x = (const float*)d_in[0];
    float* out = (float*)d_out;
    const int b = in_sizes[0] / (S * D);   // 4
    const size_t need = (size_t)in_sizes[0] * sizeof(float);
    float* vals = (ws_size >= need) ? (float*)d_ws : (float*)x;
    init_kernel<<<dim3(16 * b), dim3(256), 0, stream>>>(x, vals, out);
    merge_kernel<<<dim3(b), dim3(256), 0, stream>>>(vals, out, b);
    gather_kernel<<<dim3(b, 8), dim3(256), 0, stream>>>(vals, out);
}